// Round 24
// baseline (87.304 us; speedup 1.0000x reference)
//
#include <hip/hip_runtime.h>
#include <hip/hip_bf16.h>
#include <stdint.h>

typedef __attribute__((ext_vector_type(8))) short short8;
typedef __attribute__((ext_vector_type(4))) float f32x4;
typedef __attribute__((ext_vector_type(4))) int i32x4;
typedef __attribute__((ext_vector_type(2))) int i32x2;
typedef __attribute__((ext_vector_type(4))) unsigned short u16x4;

#define HIDDEN 768
#define HEADS 12
#define HD 64
#define NB 8
#define SEQ 1024
#define MTOT (NB*SEQ)
// Q pre-scale = (1/sqrt(768)) * log2(e): softmax then uses exp2 = raw v_exp_f32
#define QSCALE 0.05205887314427834f
// convert blocks: MTOT*HIDDEN/4/256 = 6144
#define NCVT 6144

typedef const __attribute__((address_space(1))) uint32_t* gas1_t;
typedef __attribute__((address_space(3))) uint32_t* las3_t;
#define GL_LDS16(g, l) __builtin_amdgcn_global_load_lds((gas1_t)(g), (las3_t)(l), 16, 0, 0)

static __device__ __forceinline__ unsigned short f2bf(float f){
  uint32_t u = __builtin_bit_cast(uint32_t, f);
  u += 0x7fffu + ((u >> 16) & 1u);          // round-to-nearest-even
  return (unsigned short)(u >> 16);
}
static __device__ __forceinline__ float fexp2(float x){
#if __has_builtin(__builtin_amdgcn_exp2f)
  return __builtin_amdgcn_exp2f(x);
#else
  return exp2f(x);
#endif
}

// ---- 1. prep: fp32->bf16 convert of X (blocks 0..6143) + W transpose --------
// (blocks 6144..7871 = 24x24x3). Merged to save one launch gap.
__global__ void prep_kernel(const float* __restrict__ x, unsigned short* __restrict__ xb,
                            const float* __restrict__ Wq, const float* __restrict__ Wk,
                            const float* __restrict__ Wv, unsigned short* __restrict__ Wt){
  __shared__ float t[32][33];
  int bid = blockIdx.x;
  if(bid < NCVT){
    int i = bid * 256 + threadIdx.x;             // one float4 per thread
    float4 v = reinterpret_cast<const float4*>(x)[i];
    u16x4 o;
    o[0]=f2bf(v.x); o[1]=f2bf(v.y); o[2]=f2bf(v.z); o[3]=f2bf(v.w);
    reinterpret_cast<u16x4*>(xb)[i] = o;
    return;
  }
  int b2 = bid - NCVT;                           // 24 x 24 x 3 transpose grid
  int xg = b2 % 24, yg = (b2/24) % 24, z = b2/576;
  const float* W = (z==0) ? Wq : ((z==1) ? Wk : Wv);
  unsigned short* o = Wt + (size_t)z * HIDDEN * HIDDEN;
  int n0 = xg * 32, k0 = yg * 32;
  int xl = threadIdx.x & 31, y0 = threadIdx.x >> 5;
#pragma unroll
  for(int p=0;p<4;p++){ int y = y0 + p*8; t[y][xl] = W[(size_t)(k0+y)*HIDDEN + n0 + xl]; }
  __syncthreads();
#pragma unroll
  for(int p=0;p<4;p++){ int y = y0 + p*8; o[(size_t)(n0+y)*HIDDEN + k0 + xl] = f2bf(t[xl][y]); }
}

// ---- 2. QKV projection GEMM (ROUND-14 VERIFIED, byte-identical) -------------
// C = X @ W + b; 128x128 tile, BK=64, grid 1152 1D. XCD-panel mapping: all 18
// blocks (6 xb x 3 z) sharing an A-panel land on one XCD. LDS tiles [128][64]
// bf16 (128B rows): both-sides XOR swizzle byte^=(row&7)<<4 (pre-swizzled
// global_load_lds source + swizzled ds_read). z==0 writes Q pre-scaled by
// QSCALE; z==2 writes V TRANSPOSED ([bh][d][s]).
__global__ __launch_bounds__(256, 4) void gemm_qkv_kernel(
    const unsigned short* __restrict__ Xb, const unsigned short* __restrict__ Wt,
    const float* __restrict__ bq, const float* __restrict__ bk, const float* __restrict__ bv,
    unsigned short* __restrict__ Qg, unsigned short* __restrict__ Kg, unsigned short* __restrict__ Vt)
{
  __shared__ alignas(16) unsigned short lA[128*64];   // 16 KB
  __shared__ alignas(16) unsigned short lB[128*64];   // 16 KB
  int wgid = blockIdx.x;
  int xcd = wgid & 7, idx = wgid >> 3;       // idx 0..143
  int y = xcd + 8*(idx/18);                  // A-panel id 0..63
  int within = idx % 18;
  int xb = within % 6, z = within / 6;
  const unsigned short* W = Wt + (size_t)z*HIDDEN*HIDDEN;
  const float* bias = (z==0) ? bq : ((z==1) ? bk : bv);
  int m0 = y * 128, n0 = xb * 128;
  int tid = threadIdx.x;
  int w = tid >> 6, lane = tid & 63, l16 = lane & 15, g = lane >> 4;
  int wm = w >> 1, wn = w & 1;               // 2x2 wave grid, 64x64 per wave
  f32x4 acc[4][4] = {};
  for(int kt=0; kt<HIDDEN; kt+=64){
    __syncthreads();
#pragma unroll
    for(int p=0;p<4;p++){
      int t2 = p*256 + tid;
      int r = t2 >> 3;                                // tile row (128B rows)
      int cb = (((t2 & 7) << 4) ^ ((r & 7) << 4));    // swizzled source byte
      GL_LDS16(Xb + (size_t)(m0 + r)*HIDDEN + kt + (cb >> 1), lA + p*2048 + w*512);
      GL_LDS16(W  + (size_t)(n0 + r)*HIDDEN + kt + (cb >> 1), lB + p*2048 + w*512);
    }
    __syncthreads();
#pragma unroll
    for(int kk=0;kk<2;kk++){
      short8 af[4], bf[4];
#pragma unroll
      for(int i=0;i<4;i++){
        int row = wm*64 + i*16 + l16;
        af[i] = *reinterpret_cast<const short8*>(
            reinterpret_cast<const unsigned char*>(lA) + row*128 + ((kk*64 + g*16) ^ ((row&7)<<4)));
      }
#pragma unroll
      for(int j=0;j<4;j++){
        int row = wn*64 + j*16 + l16;
        bf[j] = *reinterpret_cast<const short8*>(
            reinterpret_cast<const unsigned char*>(lB) + row*128 + ((kk*64 + g*16) ^ ((row&7)<<4)));
      }
#pragma unroll
      for(int i=0;i<4;i++)
#pragma unroll
        for(int j=0;j<4;j++)
          acc[i][j] = __builtin_amdgcn_mfma_f32_16x16x32_bf16(af[i], bf[j], acc[i][j], 0, 0, 0);
    }
  }
  if(z == 2){
    // V epilogue: bias then TRANSPOSED write Vt[bh][d][s], 4 consecutive s/lane
#pragma unroll
    for(int i=0;i<4;i++){
      int mb = m0 + wm*64 + i*16 + g*4;
      int b = mb >> 10, s = mb & 1023;       // all 4 rows stay in one (b, s+0..3)
#pragma unroll
      for(int j=0;j<4;j++){
        int n = n0 + wn*64 + j*16 + l16;
        float bi = bias[n];
        int h = n >> 6, d = n & 63;
        u16x4 pk;
#pragma unroll
        for(int r=0;r<4;r++) pk[r] = f2bf(acc[i][j][r] + bi);
        *reinterpret_cast<u16x4*>(Vt + ((size_t)(b*HEADS + h)*HD + d)*SEQ + s) = pk;
      }
    }
  } else {
    unsigned short* out = (z==0) ? Qg : Kg;
#pragma unroll
    for(int i=0;i<4;i++){
      int mb = m0 + wm*64 + i*16 + g*4;
#pragma unroll
      for(int j=0;j<4;j++){
        int n = n0 + wn*64 + j*16 + l16;       // D col = lane&15
        float bi = bias[n];
        int h = n >> 6, d = n & 63;
#pragma unroll
        for(int r=0;r<4;r++){                  // D row = 4*(lane>>4)+r
          int m = mb + r;
          int b = m >> 10, s = m & 1023;
          float cv = acc[i][j][r] + bi;
          if(z == 0) cv *= QSCALE;
          out[((size_t)(b*HEADS + h)*SEQ + s)*HD + d] = f2bf(cv);
        }
      }
    }
  }
}

// ---- 3. flash attention: QBLK=128/block, 4 waves x 32 rows, dbuf K/V --------
// (round 14 structure, + T5 s_setprio around MFMA clusters: attn blocks run
// at independent phases (3/CU, no inter-block sync) = m191's regime where
// boosting the MFMA-issuing wave's priority gained 4-7%.) SWAPPED QK^T:
// S^T = mfma(A=K, B=Q), q lane-local; P^T B-frag lane-local via sigma-
// permuted contraction axis; V^T A-frag reads absorb sigma as two
// ds_read_b64 per (jn,m); XOR swizzle over the FULL within-row offset.
__global__ __launch_bounds__(256, 3) void attn_kernel(
    const unsigned short* __restrict__ Qg, const unsigned short* __restrict__ Kg,
    const unsigned short* __restrict__ Vt, float* __restrict__ out)
{
  __shared__ alignas(16) unsigned short lK[2][64*64];  // [key][d], XOR-swizzled
  __shared__ alignas(16) unsigned short lV[2][64*64];  // [d][key], XOR-swizzled
  int wgid = blockIdx.x;
  int xcd = wgid & 7, ix = wgid >> 3;          // xcd = dispatch%8 heuristic
  int bh = xcd*12 + (ix >> 3), qb = ix & 7;    // 12 heads per XCD (3MB K/V < L2)
  int b = bh / HEADS, h = bh % HEADS;
  int tid = threadIdx.x, w = tid >> 6, lane = tid & 63, l16 = lane & 15, g = lane >> 4;

  // Q B-frags (2 row-groups x 2 d-halves) in registers for whole kernel
  const unsigned short* Qbase = Qg + ((size_t)bh*SEQ + qb*128 + w*32)*HD;
  short8 qA0 = *reinterpret_cast<const short8*>(Qbase + l16*HD + g*8);
  short8 qA1 = *reinterpret_cast<const short8*>(Qbase + l16*HD + 32 + g*8);
  short8 qB0 = *reinterpret_cast<const short8*>(Qbase + (16+l16)*HD + g*8);
  short8 qB1 = *reinterpret_cast<const short8*>(Qbase + (16+l16)*HD + 32 + g*8);

  f32x4 oacc[2][4] = {};                       // O^T: [rg][jn] d=16jn+4g+r, q=l16
  float lpart[2] = {0.f, 0.f};                 // per-lane partial row sum (q=l16)

  // per-lane constant LDS addresses (all loop offsets become immediates)
  int sw = (l16 & 7) << 4;
  int ro0 = l16*128 + ((g*16) ^ sw);           // K-frag byte offset, d-half 0
  int ro1 = l16*128 + ((64 + g*16) ^ sw);      // K-frag byte offset, d-half 1
  // V-frag b64 offsets: sigma absorbed; XOR over the FULL within-row offset
  int vo00 = l16*128 + ((      8*g) ^ sw);     // m=0, keys 4g+0..3
  int vo01 = l16*128 + ((32  + 8*g) ^ sw);     // m=0, keys 16+4g+0..3
  int vo10 = l16*128 + ((64  + 8*g) ^ sw);     // m=1, keys 32+4g+0..3
  int vo11 = l16*128 + ((96  + 8*g) ^ sw);     // m=1, keys 48+4g+0..3
  const unsigned char* lKb = reinterpret_cast<const unsigned char*>(&lK[0][0]);
  const unsigned char* lVb = reinterpret_cast<const unsigned char*>(&lV[0][0]);

  // per-lane constant staging addresses (source pre-swizzled: byte^=(row&7)<<4)
  int r0 = tid >> 3;
  int cb0 = (((tid & 7) << 4) ^ ((r0 & 7) << 4)) >> 1;             // elements
  const unsigned short* gK0 = Kg + (size_t)bh*SEQ*HD + r0*HD + cb0;
  const unsigned short* gV0 = Vt + (size_t)bh*HD*SEQ + r0*SEQ + cb0;

#define STAGE(B, t) do { \
    GL_LDS16(gK0 + (t)*4096,          &lK[B][0] + w*512); \
    GL_LDS16(gK0 + (t)*4096 + 2048,   &lK[B][0] + 2048 + w*512); \
    GL_LDS16(gV0 + (t)*64,            &lV[B][0] + w*512); \
    GL_LDS16(gV0 + (t)*64 + 32*SEQ,   &lV[B][0] + 2048 + w*512); \
  } while(0)

  // exp2 + lane-local P^T frag build + PV for one row-group
#define SMPV(SREG, LP, OA) do { \
    int Wlo[4], Whi[4]; \
    _Pragma("unroll") for(int j=0;j<4;j++){ \
      float p0=fexp2(SREG[j][0]), p1=fexp2(SREG[j][1]); \
      float p2=fexp2(SREG[j][2]), p3=fexp2(SREG[j][3]); \
      LP += (p0+p1)+(p2+p3); \
      asm("v_cvt_pk_bf16_f32 %0, %1, %2" : "=v"(Wlo[j]) : "v"(p0), "v"(p1)); \
      asm("v_cvt_pk_bf16_f32 %0, %1, %2" : "=v"(Whi[j]) : "v"(p2), "v"(p3)); } \
    __builtin_amdgcn_s_setprio(1); \
    _Pragma("unroll") for(int m=0;m<2;m++){ \
      i32x4 cc; cc[0]=Wlo[2*m]; cc[1]=Whi[2*m]; cc[2]=Wlo[2*m+1]; cc[3]=Whi[2*m+1]; \
      short8 pB = __builtin_bit_cast(short8, cc); \
      _Pragma("unroll") for(int jn=0;jn<4;jn++) \
        OA[jn] = __builtin_amdgcn_mfma_f32_16x16x32_bf16(vf[jn][m], pB, OA[jn], 0,0,0); } \
    __builtin_amdgcn_s_setprio(0); \
  } while(0)

#define TILE(CUR, kt, HAS_NEXT) do { \
    if(HAS_NEXT) STAGE((CUR)^1, (kt)+1); \
    short8 kf[4][2]; \
    _Pragma("unroll") for(int j=0;j<4;j++){ \
      kf[j][0] = *reinterpret_cast<const short8*>(lKb + (CUR)*8192 + j*2048 + ro0); \
      kf[j][1] = *reinterpret_cast<const short8*>(lKb + (CUR)*8192 + j*2048 + ro1); } \
    short8 vf[4][2]; \
    _Pragma("unroll") for(int jn=0;jn<4;jn++){ \
      { i32x2 vl = *reinterpret_cast<const i32x2*>(lVb + (CUR)*8192 + jn*2048 + vo00); \
        i32x2 vh = *reinterpret_cast<const i32x2*>(lVb + (CUR)*8192 + jn*2048 + vo01); \
        i32x4 vc; vc[0]=vl[0]; vc[1]=vl[1]; vc[2]=vh[0]; vc[3]=vh[1]; \
        vf[jn][0] = __builtin_bit_cast(short8, vc); } \
      { i32x2 vl = *reinterpret_cast<const i32x2*>(lVb + (CUR)*8192 + jn*2048 + vo10); \
        i32x2 vh = *reinterpret_cast<const i32x2*>(lVb + (CUR)*8192 + jn*2048 + vo11); \
        i32x4 vc; vc[0]=vl[0]; vc[1]=vl[1]; vc[2]=vh[0]; vc[3]=vh[1]; \
        vf[jn][1] = __builtin_bit_cast(short8, vc); } } \
    f32x4 s0[4], s1[4]; \
    __builtin_amdgcn_s_setprio(1); \
    _Pragma("unroll") for(int j=0;j<4;j++){ \
      f32x4 zz = {}; \
      zz    = __builtin_amdgcn_mfma_f32_16x16x32_bf16(kf[j][0], qA0, zz, 0,0,0); \
      s0[j] = __builtin_amdgcn_mfma_f32_16x16x32_bf16(kf[j][1], qA1, zz, 0,0,0); } \
    _Pragma("unroll") for(int j=0;j<4;j++){ \
      f32x4 zz = {}; \
      zz    = __builtin_amdgcn_mfma_f32_16x16x32_bf16(kf[j][0], qB0, zz, 0,0,0); \
      s1[j] = __builtin_amdgcn_mfma_f32_16x16x32_bf16(kf[j][1], qB1, zz, 0,0,0); } \
    __builtin_amdgcn_s_setprio(0); \
    SMPV(s0, lpart[0], oacc[0]); \
    SMPV(s1, lpart[1], oacc[1]); \
    __syncthreads(); \
  } while(0)

  STAGE(0, 0);
  __syncthreads();                             // drains vmcnt before first use

  for(int kt=0; kt<SEQ/64; kt+=2){
    TILE(0, kt, true);
    TILE(1, kt+1, (kt+1) < SEQ/64 - 1);
  }

  // epilogue: reduce row sum across g-lanes (^16, ^32), then O^T/l, f32 store
#pragma unroll
  for(int rg=0;rg<2;rg++){
    float tot = lpart[rg];
    tot += __shfl_xor(tot, 16, 64);
    tot += __shfl_xor(tot, 32, 64);
    float invl = 1.0f / tot;
    int s = qb*128 + w*32 + rg*16 + l16;
    float* orow = out + ((size_t)b*SEQ + s)*HIDDEN + h*HD + 4*g;
#pragma unroll
    for(int jn=0;jn<4;jn++){
      float4 val;
      val.x = oacc[rg][jn][0]*invl; val.y = oacc[rg][jn][1]*invl;
      val.z = oacc[rg][jn][2]*invl; val.w = oacc[rg][jn][3]*invl;
      *reinterpret_cast<float4*>(orow + 16*jn) = val;
    }
  }
#undef STAGE
#undef SMPV
#undef TILE
}

extern "C" void kernel_launch(void* const* d_in, const int* in_sizes, int n_in,
                              void* d_out, int out_size, void* d_ws, size_t ws_size,
                              hipStream_t stream) {
  const float* hs = (const float*)d_in[0];
  const float* Wq = (const float*)d_in[1];
  const float* bq = (const float*)d_in[2];
  const float* Wk = (const float*)d_in[3];
  const float* bk = (const float*)d_in[4];
  const float* Wv = (const float*)d_in[5];
  const float* bv = (const float*)d_in[6];
  float* out = (float*)d_out;

  char* ws = (char*)d_ws;
  unsigned short* Xb = (unsigned short*)ws;                          // 12.6 MB
  unsigned short* Wt = (unsigned short*)(ws + (size_t)12582912);     // 3.5 MB
  unsigned short* Qg = (unsigned short*)(ws + (size_t)16121856);
  unsigned short* Kg = Qg + (size_t)MTOT*HIDDEN;
  unsigned short* Vt = Kg + (size_t)MTOT*HIDDEN;                     // [bh][d][s]

  prep_kernel<<<NCVT + 1728, 256, 0, stream>>>(hs, Xb, Wq, Wk, Wv, Wt);
  gemm_qkv_kernel<<<1152, 256, 0, stream>>>(Xb, Wt, bq, bk, bv, Qg, Kg, Vt);
  attn_kernel<<<768, 256, 0, stream>>>(Qg, Kg, Vt, out);
}

// Round 25
// 86.513 us; speedup vs baseline: 1.0091x; 1.0091x over previous
//
#include <hip/hip_runtime.h>
#include <hip/hip_bf16.h>
#include <stdint.h>

typedef __attribute__((ext_vector_type(8))) short short8;
typedef __attribute__((ext_vector_type(4))) float f32x4;
typedef __attribute__((ext_vector_type(4))) int i32x4;
typedef __attribute__((ext_vector_type(2))) int i32x2;
typedef __attribute__((ext_vector_type(4))) unsigned short u16x4;

#define HIDDEN 768
#define HEADS 12
#define HD 64
#define NB 8
#define SEQ 1024
#define MTOT (NB*SEQ)
// Q pre-scale = (1/sqrt(768)) * log2(e): softmax then uses exp2 = raw v_exp_f32
#define QSCALE 0.05205887314427834f
// convert blocks: MTOT*HIDDEN/4/256 = 6144
#define NCVT 6144

typedef const __attribute__((address_space(1))) uint32_t* gas1_t;
typedef __attribute__((address_space(3))) uint32_t* las3_t;
#define GL_LDS16(g, l) __builtin_amdgcn_global_load_lds((gas1_t)(g), (las3_t)(l), 16, 0, 0)

static __device__ __forceinline__ unsigned short f2bf(float f){
  uint32_t u = __builtin_bit_cast(uint32_t, f);
  u += 0x7fffu + ((u >> 16) & 1u);          // round-to-nearest-even
  return (unsigned short)(u >> 16);
}
static __device__ __forceinline__ float fexp2(float x){
#if __has_builtin(__builtin_amdgcn_exp2f)
  return __builtin_amdgcn_exp2f(x);
#else
  return exp2f(x);
#endif
}

// ---- 1. prep: fp32->bf16 convert of X (blocks 0..6143) + W transpose --------
// (blocks 6144..7871 = 24x24x3). Merged to save one launch gap.
__global__ void prep_kernel(const float* __restrict__ x, unsigned short* __restrict__ xb,
                            const float* __restrict__ Wq, const float* __restrict__ Wk,
                            const float* __restrict__ Wv, unsigned short* __restrict__ Wt){
  __shared__ float t[32][33];
  int bid = blockIdx.x;
  if(bid < NCVT){
    int i = bid * 256 + threadIdx.x;             // one float4 per thread
    float4 v = reinterpret_cast<const float4*>(x)[i];
    u16x4 o;
    o[0]=f2bf(v.x); o[1]=f2bf(v.y); o[2]=f2bf(v.z); o[3]=f2bf(v.w);
    reinterpret_cast<u16x4*>(xb)[i] = o;
    return;
  }
  int b2 = bid - NCVT;                           // 24 x 24 x 3 transpose grid
  int xg = b2 % 24, yg = (b2/24) % 24, z = b2/576;
  const float* W = (z==0) ? Wq : ((z==1) ? Wk : Wv);
  unsigned short* o = Wt + (size_t)z * HIDDEN * HIDDEN;
  int n0 = xg * 32, k0 = yg * 32;
  int xl = threadIdx.x & 31, y0 = threadIdx.x >> 5;
#pragma unroll
  for(int p=0;p<4;p++){ int y = y0 + p*8; t[y][xl] = W[(size_t)(k0+y)*HIDDEN + n0 + xl]; }
  __syncthreads();
#pragma unroll
  for(int p=0;p<4;p++){ int y = y0 + p*8; o[(size_t)(n0+y)*HIDDEN + k0 + xl] = f2bf(t[xl][y]); }
}

// ---- 2. QKV projection GEMM (ROUND-14 VERIFIED, byte-identical) -------------
// C = X @ W + b; 128x128 tile, BK=64, grid 1152 1D. XCD-panel mapping: all 18
// blocks (6 xb x 3 z) sharing an A-panel land on one XCD. LDS tiles [128][64]
// bf16 (128B rows): both-sides XOR swizzle byte^=(row&7)<<4 (pre-swizzled
// global_load_lds source + swizzled ds_read). z==0 writes Q pre-scaled by
// QSCALE; z==2 writes V TRANSPOSED ([bh][d][s]).
__global__ __launch_bounds__(256, 4) void gemm_qkv_kernel(
    const unsigned short* __restrict__ Xb, const unsigned short* __restrict__ Wt,
    const float* __restrict__ bq, const float* __restrict__ bk, const float* __restrict__ bv,
    unsigned short* __restrict__ Qg, unsigned short* __restrict__ Kg, unsigned short* __restrict__ Vt)
{
  __shared__ alignas(16) unsigned short lA[128*64];   // 16 KB
  __shared__ alignas(16) unsigned short lB[128*64];   // 16 KB
  int wgid = blockIdx.x;
  int xcd = wgid & 7, idx = wgid >> 3;       // idx 0..143
  int y = xcd + 8*(idx/18);                  // A-panel id 0..63
  int within = idx % 18;
  int xb = within % 6, z = within / 6;
  const unsigned short* W = Wt + (size_t)z*HIDDEN*HIDDEN;
  const float* bias = (z==0) ? bq : ((z==1) ? bk : bv);
  int m0 = y * 128, n0 = xb * 128;
  int tid = threadIdx.x;
  int w = tid >> 6, lane = tid & 63, l16 = lane & 15, g = lane >> 4;
  int wm = w >> 1, wn = w & 1;               // 2x2 wave grid, 64x64 per wave
  f32x4 acc[4][4] = {};
  for(int kt=0; kt<HIDDEN; kt+=64){
    __syncthreads();
#pragma unroll
    for(int p=0;p<4;p++){
      int t2 = p*256 + tid;
      int r = t2 >> 3;                                // tile row (128B rows)
      int cb = (((t2 & 7) << 4) ^ ((r & 7) << 4));    // swizzled source byte
      GL_LDS16(Xb + (size_t)(m0 + r)*HIDDEN + kt + (cb >> 1), lA + p*2048 + w*512);
      GL_LDS16(W  + (size_t)(n0 + r)*HIDDEN + kt + (cb >> 1), lB + p*2048 + w*512);
    }
    __syncthreads();
#pragma unroll
    for(int kk=0;kk<2;kk++){
      short8 af[4], bf[4];
#pragma unroll
      for(int i=0;i<4;i++){
        int row = wm*64 + i*16 + l16;
        af[i] = *reinterpret_cast<const short8*>(
            reinterpret_cast<const unsigned char*>(lA) + row*128 + ((kk*64 + g*16) ^ ((row&7)<<4)));
      }
#pragma unroll
      for(int j=0;j<4;j++){
        int row = wn*64 + j*16 + l16;
        bf[j] = *reinterpret_cast<const short8*>(
            reinterpret_cast<const unsigned char*>(lB) + row*128 + ((kk*64 + g*16) ^ ((row&7)<<4)));
      }
#pragma unroll
      for(int i=0;i<4;i++)
#pragma unroll
        for(int j=0;j<4;j++)
          acc[i][j] = __builtin_amdgcn_mfma_f32_16x16x32_bf16(af[i], bf[j], acc[i][j], 0, 0, 0);
    }
  }
  if(z == 2){
    // V epilogue: bias then TRANSPOSED write Vt[bh][d][s], 4 consecutive s/lane
#pragma unroll
    for(int i=0;i<4;i++){
      int mb = m0 + wm*64 + i*16 + g*4;
      int b = mb >> 10, s = mb & 1023;       // all 4 rows stay in one (b, s+0..3)
#pragma unroll
      for(int j=0;j<4;j++){
        int n = n0 + wn*64 + j*16 + l16;
        float bi = bias[n];
        int h = n >> 6, d = n & 63;
        u16x4 pk;
#pragma unroll
        for(int r=0;r<4;r++) pk[r] = f2bf(acc[i][j][r] + bi);
        *reinterpret_cast<u16x4*>(Vt + ((size_t)(b*HEADS + h)*HD + d)*SEQ + s) = pk;
      }
    }
  } else {
    unsigned short* out = (z==0) ? Qg : Kg;
#pragma unroll
    for(int i=0;i<4;i++){
      int mb = m0 + wm*64 + i*16 + g*4;
#pragma unroll
      for(int j=0;j<4;j++){
        int n = n0 + wn*64 + j*16 + l16;       // D col = lane&15
        float bi = bias[n];
        int h = n >> 6, d = n & 63;
#pragma unroll
        for(int r=0;r<4;r++){                  // D row = 4*(lane>>4)+r
          int m = mb + r;
          int b = m >> 10, s = m & 1023;
          float cv = acc[i][j][r] + bi;
          if(z == 0) cv *= QSCALE;
          out[((size_t)(b*HEADS + h)*SEQ + s)*HD + d] = f2bf(cv);
        }
      }
    }
  }
}

// ---- 3. flash attention: QBLK=128/block, 4 waves x 32 rows, dbuf K/V --------
// (verified round 14 — unchanged) SWAPPED QK^T: S^T = mfma(A=K, B=Q), q
// lane-local; P^T B-frag lane-local via sigma-permuted contraction axis;
// V^T A-frag reads absorb sigma as two ds_read_b64 per (jn,m); XOR swizzle
// over the FULL within-row offset. Row-sum reduced once in the epilogue.
__global__ __launch_bounds__(256, 3) void attn_kernel(
    const unsigned short* __restrict__ Qg, const unsigned short* __restrict__ Kg,
    const unsigned short* __restrict__ Vt, float* __restrict__ out)
{
  __shared__ alignas(16) unsigned short lK[2][64*64];  // [key][d], XOR-swizzled
  __shared__ alignas(16) unsigned short lV[2][64*64];  // [d][key], XOR-swizzled
  int wgid = blockIdx.x;
  int xcd = wgid & 7, ix = wgid >> 3;          // xcd = dispatch%8 heuristic
  int bh = xcd*12 + (ix >> 3), qb = ix & 7;    // 12 heads per XCD (3MB K/V < L2)
  int b = bh / HEADS, h = bh % HEADS;
  int tid = threadIdx.x, w = tid >> 6, lane = tid & 63, l16 = lane & 15, g = lane >> 4;

  // Q B-frags (2 row-groups x 2 d-halves) in registers for whole kernel
  const unsigned short* Qbase = Qg + ((size_t)bh*SEQ + qb*128 + w*32)*HD;
  short8 qA0 = *reinterpret_cast<const short8*>(Qbase + l16*HD + g*8);
  short8 qA1 = *reinterpret_cast<const short8*>(Qbase + l16*HD + 32 + g*8);
  short8 qB0 = *reinterpret_cast<const short8*>(Qbase + (16+l16)*HD + g*8);
  short8 qB1 = *reinterpret_cast<const short8*>(Qbase + (16+l16)*HD + 32 + g*8);

  f32x4 oacc[2][4] = {};                       // O^T: [rg][jn] d=16jn+4g+r, q=l16
  float lpart[2] = {0.f, 0.f};                 // per-lane partial row sum (q=l16)

  // per-lane constant LDS addresses (all loop offsets become immediates)
  int sw = (l16 & 7) << 4;
  int ro0 = l16*128 + ((g*16) ^ sw);           // K-frag byte offset, d-half 0
  int ro1 = l16*128 + ((64 + g*16) ^ sw);      // K-frag byte offset, d-half 1
  // V-frag b64 offsets: sigma absorbed; XOR over the FULL within-row offset
  int vo00 = l16*128 + ((      8*g) ^ sw);     // m=0, keys 4g+0..3
  int vo01 = l16*128 + ((32  + 8*g) ^ sw);     // m=0, keys 16+4g+0..3
  int vo10 = l16*128 + ((64  + 8*g) ^ sw);     // m=1, keys 32+4g+0..3
  int vo11 = l16*128 + ((96  + 8*g) ^ sw);     // m=1, keys 48+4g+0..3
  const unsigned char* lKb = reinterpret_cast<const unsigned char*>(&lK[0][0]);
  const unsigned char* lVb = reinterpret_cast<const unsigned char*>(&lV[0][0]);

  // per-lane constant staging addresses (source pre-swizzled: byte^=(row&7)<<4)
  int r0 = tid >> 3;
  int cb0 = (((tid & 7) << 4) ^ ((r0 & 7) << 4)) >> 1;             // elements
  const unsigned short* gK0 = Kg + (size_t)bh*SEQ*HD + r0*HD + cb0;
  const unsigned short* gV0 = Vt + (size_t)bh*HD*SEQ + r0*SEQ + cb0;

#define STAGE(B, t) do { \
    GL_LDS16(gK0 + (t)*4096,          &lK[B][0] + w*512); \
    GL_LDS16(gK0 + (t)*4096 + 2048,   &lK[B][0] + 2048 + w*512); \
    GL_LDS16(gV0 + (t)*64,            &lV[B][0] + w*512); \
    GL_LDS16(gV0 + (t)*64 + 32*SEQ,   &lV[B][0] + 2048 + w*512); \
  } while(0)

  // exp2 + lane-local P^T frag build + PV for one row-group
#define SMPV(SREG, LP, OA) do { \
    int Wlo[4], Whi[4]; \
    _Pragma("unroll") for(int j=0;j<4;j++){ \
      float p0=fexp2(SREG[j][0]), p1=fexp2(SREG[j][1]); \
      float p2=fexp2(SREG[j][2]), p3=fexp2(SREG[j][3]); \
      LP += (p0+p1)+(p2+p3); \
      asm("v_cvt_pk_bf16_f32 %0, %1, %2" : "=v"(Wlo[j]) : "v"(p0), "v"(p1)); \
      asm("v_cvt_pk_bf16_f32 %0, %1, %2" : "=v"(Whi[j]) : "v"(p2), "v"(p3)); } \
    _Pragma("unroll") for(int m=0;m<2;m++){ \
      i32x4 cc; cc[0]=Wlo[2*m]; cc[1]=Whi[2*m]; cc[2]=Wlo[2*m+1]; cc[3]=Whi[2*m+1]; \
      short8 pB = __builtin_bit_cast(short8, cc); \
      _Pragma("unroll") for(int jn=0;jn<4;jn++) \
        OA[jn] = __builtin_amdgcn_mfma_f32_16x16x32_bf16(vf[jn][m], pB, OA[jn], 0,0,0); } \
  } while(0)

#define TILE(CUR, kt, HAS_NEXT) do { \
    if(HAS_NEXT) STAGE((CUR)^1, (kt)+1); \
    short8 kf[4][2]; \
    _Pragma("unroll") for(int j=0;j<4;j++){ \
      kf[j][0] = *reinterpret_cast<const short8*>(lKb + (CUR)*8192 + j*2048 + ro0); \
      kf[j][1] = *reinterpret_cast<const short8*>(lKb + (CUR)*8192 + j*2048 + ro1); } \
    short8 vf[4][2]; \
    _Pragma("unroll") for(int jn=0;jn<4;jn++){ \
      { i32x2 vl = *reinterpret_cast<const i32x2*>(lVb + (CUR)*8192 + jn*2048 + vo00); \
        i32x2 vh = *reinterpret_cast<const i32x2*>(lVb + (CUR)*8192 + jn*2048 + vo01); \
        i32x4 vc; vc[0]=vl[0]; vc[1]=vl[1]; vc[2]=vh[0]; vc[3]=vh[1]; \
        vf[jn][0] = __builtin_bit_cast(short8, vc); } \
      { i32x2 vl = *reinterpret_cast<const i32x2*>(lVb + (CUR)*8192 + jn*2048 + vo10); \
        i32x2 vh = *reinterpret_cast<const i32x2*>(lVb + (CUR)*8192 + jn*2048 + vo11); \
        i32x4 vc; vc[0]=vl[0]; vc[1]=vl[1]; vc[2]=vh[0]; vc[3]=vh[1]; \
        vf[jn][1] = __builtin_bit_cast(short8, vc); } } \
    f32x4 s0[4], s1[4]; \
    _Pragma("unroll") for(int j=0;j<4;j++){ \
      f32x4 zz = {}; \
      zz    = __builtin_amdgcn_mfma_f32_16x16x32_bf16(kf[j][0], qA0, zz, 0,0,0); \
      s0[j] = __builtin_amdgcn_mfma_f32_16x16x32_bf16(kf[j][1], qA1, zz, 0,0,0); } \
    _Pragma("unroll") for(int j=0;j<4;j++){ \
      f32x4 zz = {}; \
      zz    = __builtin_amdgcn_mfma_f32_16x16x32_bf16(kf[j][0], qB0, zz, 0,0,0); \
      s1[j] = __builtin_amdgcn_mfma_f32_16x16x32_bf16(kf[j][1], qB1, zz, 0,0,0); } \
    SMPV(s0, lpart[0], oacc[0]); \
    SMPV(s1, lpart[1], oacc[1]); \
    __syncthreads(); \
  } while(0)

  STAGE(0, 0);
  __syncthreads();                             // drains vmcnt before first use

  for(int kt=0; kt<SEQ/64; kt+=2){
    TILE(0, kt, true);
    TILE(1, kt+1, (kt+1) < SEQ/64 - 1);
  }

  // epilogue: reduce row sum across g-lanes (^16, ^32), then O^T/l, f32 store
#pragma unroll
  for(int rg=0;rg<2;rg++){
    float tot = lpart[rg];
    tot += __shfl_xor(tot, 16, 64);
    tot += __shfl_xor(tot, 32, 64);
    float invl = 1.0f / tot;
    int s = qb*128 + w*32 + rg*16 + l16;
    float* orow = out + ((size_t)b*SEQ + s)*HIDDEN + h*HD + 4*g;
#pragma unroll
    for(int jn=0;jn<4;jn++){
      float4 val;
      val.x = oacc[rg][jn][0]*invl; val.y = oacc[rg][jn][1]*invl;
      val.z = oacc[rg][jn][2]*invl; val.w = oacc[rg][jn][3]*invl;
      *reinterpret_cast<float4*>(orow + 16*jn) = val;
    }
  }
#undef STAGE
#undef SMPV
#undef TILE
}

extern "C" void kernel_launch(void* const* d_in, const int* in_sizes, int n_in,
                              void* d_out, int out_size, void* d_ws, size_t ws_size,
                              hipStream_t stream) {
  const float* hs = (const float*)d_in[0];
  const float* Wq = (const float*)d_in[1];
  const float* bq = (const float*)d_in[2];
  const float* Wk = (const float*)d_in[3];
  const float* bk = (const float*)d_in[4];
  const float* Wv = (const float*)d_in[5];
  const float* bv = (const float*)d_in[6];
  float* out = (float*)d_out;

  char* ws = (char*)d_ws;
  unsigned short* Xb = (unsigned short*)ws;                          // 12.6 MB
  unsigned short* Wt = (unsigned short*)(ws + (size_t)12582912);     // 3.5 MB
  unsigned short* Qg = (unsigned short*)(ws + (size_t)16121856);
  unsigned short* Kg = Qg + (size_t)MTOT*HIDDEN;
  unsigned short* Vt = Kg + (size_t)MTOT*HIDDEN;                     // [bh][d][s]

  prep_kernel<<<NCVT + 1728, 256, 0, stream>>>(hs, Xb, Wq, Wk, Wv, Wt);
  gemm_qkv_kernel<<<1152, 256, 0, stream>>>(Xb, Wt, bq, bk, bv, Qg, Kg, Vt);
  attn_kernel<<<768, 256, 0, stream>>>(Qg, Kg, Vt, out);
}